// Round 13
// baseline (225.771 us; speedup 1.0000x reference)
//
#include <hip/hip_runtime.h>
#include <math.h>

// DigitCaps dynamic routing, MI355X (gfx950). Round 13: recompute design with
// the reduction hoisted OUT of the inner loop.
// B=256, I=1152 (dim 8), O=10 (dim 16), 3 routing iters.
//
// R11 (49 us, VALUBusy 58%) spent its stall on 160 in-loop ds_swizzle ops
// (il-reduce per bb per o) + 80 vs_s LDS reads. R12's (256,5) spilled again
// (VGPR 48, +55 MB scratch traffic) -> launch_bounds stays (256,4), always.
//
// New mapping: thread = (bb = t>>5, il2 = (t>>4)&1, d = t&15); loops over its
// 8 capsules i = itile*16 + il2*8 + k. b is FIXED per thread -> acc[10]
// accumulates privately; the block reduction is 10 shfl_xor(16) at the END
// (160 DS -> 10). vsum rows live in 10 registers (one-time global loads,
// L2/L3-hot). No pacc, no vs_s: LDS = 4 KB, ONE barrier.
// W slice per itile = 80 KB, L2-pinned by itile%8 XCD affinity (measured
// FETCH 8 MB in R11 confirms W stays cache-resident).
//
// b_ij identity: logits at iter k = u.(v0+..+v_{k-1}) = u.vsum.
// Pipeline: k_pass<0> -> k_squash<0>(pre=0.1) -> k_pass<1> -> k_squash<1>
//           -> k_pass<1> -> k_squash<2> -> out.

constexpr int Bc  = 256;
constexpr int Ic  = 1152;
constexpr int Oc  = 10;
constexpr int DOc = 16;
constexpr int ODc = 160;
constexpr int ITILES = 72;
constexpr int BB  = 8;               // b per block
constexpr int BT  = Bc / BB;         // 32 btiles

// Sum over the aligned 16-lane group, result in all 16 lanes. Pure VALU (DPP).
__device__ __forceinline__ float dpp16_sum(float v) {
    int s;
    s = __builtin_amdgcn_update_dpp(0, __float_as_int(v), 0xB1, 0xF, 0xF, true);
    v += __int_as_float(s);
    s = __builtin_amdgcn_update_dpp(0, __float_as_int(v), 0x4E, 0xF, 0xF, true);
    v += __int_as_float(s);
    s = __builtin_amdgcn_update_dpp(0, __float_as_int(v), 0x124, 0xF, 0xF, true);
    v += __int_as_float(s);
    s = __builtin_amdgcn_update_dpp(0, __float_as_int(v), 0x128, 0xF, 0xF, true);
    v += __int_as_float(s);
    return v;
}

// ---------------------------------------------------------------- k_pass
// grid 2304 = 72 itiles x 32 btiles, 256 threads, launch_bounds(256,4).
// PASS 0: acc[o] += u[o] (0.1 folded into squash).  PASS 1: softmax routing.
template <int PASS>
__global__ __launch_bounds__(256, 4) void k_pass(const float* __restrict__ x,
                                                 const float* __restrict__ W,
                                                 const float* __restrict__ vsum,
                                                 float* __restrict__ partial) {
    const int bx    = blockIdx.x;
    const int itile = bx % ITILES;      // 72%8==0: itile pinned to an XCD
    const int btile = bx / ITILES;
    const int t     = threadIdx.x;
    const int d     = t & 15;
    const int il2   = (t >> 4) & 1;
    const int bb    = t >> 5;
    const int b     = btile * BB + bb;

    __shared__ __align__(16) float xs[BB * 128];   // 4 KB [bb][ii*8+k]

    // stage x[b0:b0+8][itile*16:+16][8]: 256 float4, one per thread
    {
        int sbb = t >> 5;
        int r   = t & 31;
        ((float4*)xs)[t] =
            ((const float4*)(x + (size_t)(btile * BB + sbb) * (Ic * 8) +
                             itile * 128))[r];
    }

    // vsum row for this thread's (b, d): 10 scalars in registers (L2/L3-hot)
    float vsr[Oc];
    if (PASS == 1) {
#pragma unroll
        for (int o = 0; o < Oc; ++o)
            vsr[o] = vsum[(size_t)b * ODc + o * 16 + d];
    }
    __syncthreads();

    float acc[Oc];
#pragma unroll
    for (int o = 0; o < Oc; ++o) acc[o] = 0.f;

#pragma unroll 1
    for (int k = 0; k < 8; ++k) {
        const int i_loc = il2 * 8 + k;
        const int i     = itile * 16 + i_loc;
        const float4 xa = *((const float4*)(xs + bb * 128 + i_loc * 8));
        const float4 xb = *((const float4*)(xs + bb * 128 + i_loc * 8 + 4));
        const float* wbase = W + (((size_t)i * Oc) * DOc + d) * 8;
        float u[Oc];
#pragma unroll
        for (int o = 0; o < Oc; ++o) {
            const float4* wp = (const float4*)(wbase + o * 128);
            const float4 w0 = wp[0];
            const float4 w1 = wp[1];
            u[o] = w0.x * xa.x + w0.y * xa.y + w0.z * xa.z + w0.w * xa.w +
                   w1.x * xb.x + w1.y * xb.y + w1.z * xb.z + w1.w * xb.w;
        }
        if (PASS == 1) {
            // logits via DPP 16-lane reduce over d (VALU, no DS traffic)
            float c[Oc];
#pragma unroll
            for (int o = 0; o < Oc; ++o) c[o] = dpp16_sum(u[o] * vsr[o]);
            float m = c[0];
#pragma unroll
            for (int o = 1; o < Oc; ++o) m = fmaxf(m, c[o]);
            float se = 0.f;
#pragma unroll
            for (int o = 0; o < Oc; ++o) {
                c[o] = __expf(c[o] - m);
                se += c[o];
            }
            const float inv = 1.f / se;
#pragma unroll
            for (int o = 0; o < Oc; ++o) acc[o] += (c[o] * inv) * u[o];
        } else {
#pragma unroll
            for (int o = 0; o < Oc; ++o) acc[o] += u[o];
        }
    }

    // block reduction: only across the two il2 halves (xor lane-bit 4),
    // then lanes with il2==0 write partial[itile][b][o*16+d].
    float* pb = partial + (size_t)itile * (Bc * ODc) + (size_t)b * ODc + d;
#pragma unroll
    for (int o = 0; o < Oc; ++o) {
        float a = acc[o] + __shfl_xor(acc[o], 16);
        if (il2 == 0) pb[o * 16] = a;
    }
}

// ---------------------------------------------------------------- k_squash
// MODE 0: vsum = v   MODE 1: vsum += v   MODE 2: out = v
template <int MODE>
__global__ __launch_bounds__(256) void k_squash(const float* __restrict__ part,
                                                float* __restrict__ vsum,
                                                float* __restrict__ out,
                                                float pre) {
    const int b = blockIdx.x;
    const int t = threadIdx.x;
    if (t >= ODc) return;
    float s = 0.f;
#pragma unroll 8
    for (int p = 0; p < ITILES; ++p)
        s += part[(size_t)p * (Bc * ODc) + b * ODc + t];
    s *= pre;
    float sq = dpp16_sum(s * s);
    float scale = sq / ((1.f + sq) * sqrtf(sq));
    float v = s * scale;
    if (MODE == 0) vsum[b * ODc + t] = v;
    if (MODE == 1) vsum[b * ODc + t] += v;
    if (MODE == 2) out[(size_t)b * ODc + t] = v;
}

// ---------------------------------------------------------------- fallback
__global__ void __launch_bounds__(1024, 4)
digitcaps_fallback(const float* __restrict__ x, const float* __restrict__ W,
                   float* __restrict__ out) {
    const int b = blockIdx.x, t = threadIdx.x;
    const int lane = t & 63, wid = t >> 6, d = t & 15, iblk = t >> 4;
    __shared__ __align__(16) float xs[Ic * 8];
    __shared__ __align__(16) float red[16 * ODc];
    __shared__ __align__(16) float svec[ODc], vcur[ODc], vsum[ODc];
    {
        const float4* xg = (const float4*)(x + (size_t)b * (Ic * 8));
        float4* xl = (float4*)xs;
        for (int j = t; j < Ic * 2; j += 1024) xl[j] = xg[j];
    }
    if (t < ODc) vsum[t] = 0.f;
    __syncthreads();
    float acc[Oc], vsr[Oc];
    for (int it = 0; it < 3; ++it) {
#pragma unroll
        for (int o = 0; o < Oc; ++o) { acc[o] = 0.f; vsr[o] = vsum[o * 16 + d]; }
#pragma unroll 1
        for (int chk = 0; chk < 18; ++chk) {
            const int i = chk * 64 + iblk;
            const float4 xa = ((const float4*)(xs + i * 8))[0];
            const float4 xb = ((const float4*)(xs + i * 8))[1];
            const float* wb = W + (((size_t)i * Oc) * DOc + d) * 8;
            float uo[Oc];
#pragma unroll
            for (int o = 0; o < Oc; ++o) {
                const float4* wp = (const float4*)(wb + o * 128);
                float4 w0 = wp[0], w1 = wp[1];
                uo[o] = w0.x * xa.x + w0.y * xa.y + w0.z * xa.z + w0.w * xa.w +
                        w1.x * xb.x + w1.y * xb.y + w1.z * xb.z + w1.w * xb.w;
            }
            float cc[Oc];
            if (it > 0) {
#pragma unroll
                for (int o = 0; o < Oc; ++o) cc[o] = dpp16_sum(uo[o] * vsr[o]);
                float m = cc[0];
#pragma unroll
                for (int o = 1; o < Oc; ++o) m = fmaxf(m, cc[o]);
                float se = 0.f;
#pragma unroll
                for (int o = 0; o < Oc; ++o) { cc[o] = __expf(cc[o] - m); se += cc[o]; }
                float inv = 1.f / se;
#pragma unroll
                for (int o = 0; o < Oc; ++o) acc[o] += cc[o] * inv * uo[o];
            } else {
#pragma unroll
                for (int o = 0; o < Oc; ++o) acc[o] += 0.1f * uo[o];
            }
        }
#pragma unroll
        for (int o = 0; o < Oc; ++o) {
            float a = acc[o];
            a += __shfl_xor(a, 16);
            a += __shfl_xor(a, 32);
            if (lane < 16) red[wid * ODc + o * 16 + lane] = a;
        }
        __syncthreads();
        if (t < ODc) {
            float s = 0.f;
#pragma unroll
            for (int w = 0; w < 16; ++w) s += red[w * ODc + t];
            svec[t] = s;
        }
        __syncthreads();
        if (t < Oc) {
            float sq = 0.f;
#pragma unroll
            for (int dd = 0; dd < DOc; ++dd) sq += svec[t * 16 + dd] * svec[t * 16 + dd];
            float sc = sq / ((1.f + sq) * sqrtf(sq));
#pragma unroll
            for (int dd = 0; dd < DOc; ++dd) {
                float v = svec[t * 16 + dd] * sc;
                vcur[t * 16 + dd] = v;
                vsum[t * 16 + dd] += v;
            }
        }
        __syncthreads();
    }
    if (t < ODc) out[(size_t)b * ODc + t] = vcur[t];
}

// ---------------------------------------------------------------- launcher
extern "C" void kernel_launch(void* const* d_in, const int* in_sizes, int n_in,
                              void* d_out, int out_size, void* d_ws, size_t ws_size,
                              hipStream_t stream) {
    (void)in_sizes; (void)n_in; (void)out_size;
    const float* x = (const float*)d_in[0];   // [256,1152,8]
    const float* W = (const float*)d_in[1];   // [1152,10,16,8]
    float* out     = (float*)d_out;           // [256,10,16]

    const size_t PART_B = (size_t)ITILES * Bc * ODc * sizeof(float); // 11.8 MB
    const size_t VSUM_B = (size_t)Bc * ODc * sizeof(float);          // 160 KB

    float* partial = (float*)d_ws;
    float* vsum    = (float*)((char*)d_ws + PART_B);

    if (ws_size >= PART_B + VSUM_B) {
        dim3 pg(ITILES * BT), pb(256);
        hipLaunchKernelGGL((k_pass<0>), pg, pb, 0, stream, x, W, nullptr, partial);
        hipLaunchKernelGGL((k_squash<0>), dim3(Bc), dim3(256), 0, stream,
                           partial, vsum, out, 0.1f);
        hipLaunchKernelGGL((k_pass<1>), pg, pb, 0, stream, x, W, vsum, partial);
        hipLaunchKernelGGL((k_squash<1>), dim3(Bc), dim3(256), 0, stream,
                           partial, vsum, out, 1.f);
        hipLaunchKernelGGL((k_pass<1>), pg, pb, 0, stream, x, W, vsum, partial);
        hipLaunchKernelGGL((k_squash<2>), dim3(Bc), dim3(256), 0, stream,
                           partial, vsum, out, 1.f);
    } else {
        hipLaunchKernelGGL(digitcaps_fallback, dim3(Bc), dim3(1024), 0, stream,
                           x, W, out);
    }
}